// Round 15
// baseline (251.520 us; speedup 1.0000x reference)
//
#include <hip/hip_runtime.h>
#include <hip/hip_bf16.h>
#include <cstdint>
#include <cstddef>

// B=4, S=2048, D=768 causal attention, fp32 in/out, f16 MFMA compute.
// R15: fused v5 - producer/consumer wave specialization (TLP, not ILP).
// Evidence: FOUR source-level ILP attempts (dist-2/dist-3/8-reg batches x2)
// all defeated by hipcc load-sinking (VGPR stuck at 60). Latency model:
// 4 waves/SIMD x ~20% duty = MfmaUtil 13.6%. Fix: 1024 thr / 16 waves:
// waves 0-7 produce QK(kt)+exp->sP[kt&1] (+rowsum), waves 8-15 consume
// PV(kt-1) from sP[(kt-1)&1]. Per-wave chain HALVES (24 loads/tile) and
// resident waves DOUBLE (2 blk/CU x 16 = 32 waves/CU, needs VGPR<=64 ->
// __launch_bounds__(1024,8); per-role state is small: ~30 prod/~54 cons).
// One barrier/tile (double-buffered sP). Load batching removed (useless).
// g0 (qkv) and cvt: frozen at verified state.
// Fragment-tiled layout: elem(r,c) at ((r>>4)*(C/8)+(c>>3))*128+(r&15)*8+(c&7)

typedef _Float16 f16x8 __attribute__((ext_vector_type(8)));
typedef float    f32x4 __attribute__((ext_vector_type(4)));

#define SOFTMAX_SCALE 0.036084391824351615f  // 1/sqrt(768)

// fragment-tiled element index; cd3 = C>>3 (chunks per 16-row group)
__device__ __forceinline__ int tix(int r, int c, int cd3) {
    return ((r >> 4) * cd3 + (c >> 3)) * 128 + ((r & 15) << 3) + (c & 7);
}

// ---------------- g0: QKV projection (verified, frozen) -----------------
__global__ __launch_bounds__(256, 2) void gemm_qkv(
    const _Float16* __restrict__ A, const _Float16* __restrict__ Bt,
    _Float16* __restrict__ OQ, _Float16* __restrict__ OK, _Float16* __restrict__ OV)
{
    const int flat = blockIdx.y * 18 + blockIdx.x;     // 0..1151, x-fast
    const int swz  = (flat & 7) * 144 + (flat >> 3);   // bijective (1152%8==0)
    const int tm = swz / 18, tn = swz % 18;
    const int m0 = tm * 128, n0 = tn * 128;
    const int tid  = threadIdx.x;
    const int lane = tid & 63, wave = tid >> 6;
    const int wm = (wave >> 1) * 64, wn = (wave & 1) * 64;
    const int qr = lane >> 4, ql = lane & 15;

    __shared__ _Float16 sA[128 * 64];

    const _Float16* Ab = A + (long long)m0 * 768;

    const _Float16* pB[4];
#pragma unroll
    for (int ni = 0; ni < 4; ++ni) {
        const int r0 = n0 + wn + ni * 16;
        pB[ni] = Bt + ((r0 >> 4) * 96 + qr) * 128 + ql * 8;
    }

    const int kIters = 768 / 64;

    f32x4 acc[4][4];
#pragma unroll
    for (int i = 0; i < 4; ++i)
#pragma unroll
        for (int j = 0; j < 4; ++j) acc[i][j] = (f32x4){0.f, 0.f, 0.f, 0.f};

    int sra[4], sgc[4];
#pragma unroll
    for (int t = 0; t < 4; ++t) {
        const int c = t * 256 + tid, r = c >> 3;
        sra[t] = r; sgc[t] = (c & 7) ^ (r & 7);
    }

    f16x8 pa[4];
    auto loadA = [&](int kt) {
        const int kk = kt * 64;
#pragma unroll
        for (int t = 0; t < 4; ++t)
            pa[t] = *(const f16x8*)(Ab + sra[t] * 768 + kk + sgc[t] * 8);
    };

    loadA(0);
    for (int kt = 0; kt < kIters; ++kt) {
#pragma unroll
        for (int t = 0; t < 4; ++t) ((f16x8*)sA)[t * 256 + tid] = pa[t];
        __syncthreads();

        f16x8 bF[2][4];
#pragma unroll
        for (int ks = 0; ks < 2; ++ks)
#pragma unroll
            for (int ni = 0; ni < 4; ++ni)
                bF[ks][ni] = *(const f16x8*)(pB[ni] + kt * 1024 + ks * 512);

        if (kt + 1 < kIters) loadA(kt + 1);

#pragma unroll
        for (int ks = 0; ks < 2; ++ks) {
            f16x8 aF[4];
#pragma unroll
            for (int mi = 0; mi < 4; ++mi) {
                const int r = wm + mi * 16 + ql;
                const int sc = (ks * 4 + qr) ^ (r & 7);
                aF[mi] = *(const f16x8*)&sA[r * 64 + sc * 8];
            }
#pragma unroll
            for (int mi = 0; mi < 4; ++mi)
#pragma unroll
                for (int ni = 0; ni < 4; ++ni)
                    acc[mi][ni] = __builtin_amdgcn_mfma_f32_16x16x32_f16(
                        aF[mi], bF[ks][ni], acc[mi][ni], 0, 0, 0);
        }
        __syncthreads();
    }

#pragma unroll
    for (int mi = 0; mi < 4; ++mi) {
#pragma unroll
        for (int ni = 0; ni < 4; ++ni) {
            const f32x4 v = acc[mi][ni];
            const int mbase = m0 + wm + mi * 16 + qr * 4;
            const int n     = n0 + wn + ni * 16 + ql;
#pragma unroll
            for (int r = 0; r < 4; ++r) {
                const int m = mbase + r;
                const float val = v[r];
                if (n < 768) {
                    // Q: ROW-MAJOR, pre-scaled (A-side of fused LDS path)
                    OQ[(long long)m * 768 + n] = (_Float16)(val * SOFTMAX_SCALE);
                } else if (n < 1536) {
                    OK[tix(m, n - 768, 96)] = (_Float16)val;
                } else {
                    const int b = m >> 11, s = m & 2047;
                    OV[tix(b * 768 + (n - 1536), s, 256)] = (_Float16)val;
                }
            }
        }
    }
}

// ---------------- fused v5: producer/consumer wave split ----------------
__global__ __launch_bounds__(1024, 8) void fused_attn(
    const _Float16* __restrict__ Qr, const _Float16* __restrict__ Kt,
    const _Float16* __restrict__ Vtt, float* __restrict__ out)
{
    __shared__ _Float16 sQ[16 * 768];    // fragment-tiled: idx8 = c8*16 + r
    __shared__ _Float16 sP[2][16 * 128]; // double-buffered P relay
    __shared__ float    sRS[8][16];

    // Block -> (batch, stripe): XCD x gets 32 complete complementary pairs
    // (544 tile-units each, balanced); pair members 32-apart in dispatch.
    const int b   = blockIdx.x;                 // 0..511
    const int x   = b & 7, j = b >> 3;          // XCD, 0..63
    const int m_  = (j >> 5) & 1;               // pair member
    const int pg  = x * 32 + (j & 31);          // pair 0..255
    const int bz  = pg >> 6;                    // batch 0..3
    const int pr  = pg & 63;                    // pair in batch
    const int s   = m_ ? pr : (127 - pr);       // stripe 0..127 (heavy first)
    const int m0  = s * 16;

    const int tid = threadIdx.x;
    const int lane = tid & 63, w = tid >> 6;    // wave 0..15
    const int qr = lane >> 4, ql = lane & 15;
    const bool isProd = (w < 8);
    const int wq_ = w & 7;                      // producer col group 0..7
    const int wv_ = w & 7;                      // consumer col group 0..7

    // Producer: Kt row chunk base (kv tile 0): row = bz*2048 + 16*wq_
    const _Float16* pK0 = Kt + (((bz * 2048 + 16 * wq_) >> 4) * 96 + qr) * 128 + ql * 8;
    // Consumer: Vtt row chunk base: row = bz*768 + 96*wv_ (+16*ni later)
    const _Float16* pV0 = Vtt + (((bz * 768 + 96 * wv_) >> 4) * 256 + qr) * 128 + ql * 8;

    // stage Q (16x768) fragment-tiled into LDS; 1536 chunks, 1024 threads
    {
        const int jj0 = tid;                    // 0..1023
        ((f16x8*)sQ)[( jj0 >> 4) * 16 + (jj0 & 15)] =
            *(const f16x8*)(Qr + (long long)(bz * 2048 + m0 + (jj0 & 15)) * 768
                            + (jj0 >> 4) * 8);
        if (tid < 512) {
            const int jj = 1024 + tid;          // 1024..1535
            ((f16x8*)sQ)[(jj >> 4) * 16 + (jj & 15)] =
                *(const f16x8*)(Qr + (long long)(bz * 2048 + m0 + (jj & 15)) * 768
                                + (jj >> 4) * 8);
        }
    }
    __syncthreads();

    const int nt = (s >> 3) + 1;                // causal KV tiles of 128

    f32x4 oacc[6];
#pragma unroll
    for (int i = 0; i < 6; ++i) oacc[i] = (f32x4){0.f, 0.f, 0.f, 0.f};
    float prs0 = 0.f, prs1 = 0.f, prs2 = 0.f, prs3 = 0.f;

    // ---- producer: QK tile (2 acc chains, simple loads) + exp + P->LDS ----
    auto qk_exp = [&](int kt2) {
        const _Float16* pKt = pK0 + (long long)kt2 * 98304;
        f32x4 s0 = (f32x4){0.f, 0.f, 0.f, 0.f};
        f32x4 s1 = (f32x4){0.f, 0.f, 0.f, 0.f};
#pragma unroll
        for (int ks = 0; ks < 24; ks += 2) {
            const f16x8 q0 = *(const f16x8*)&sQ[(ks * 4 + qr) * 128 + ql * 8];
            const f16x8 k0 = *(const f16x8*)(pKt + ks * 512);
            const f16x8 q1 = *(const f16x8*)&sQ[((ks + 1) * 4 + qr) * 128 + ql * 8];
            const f16x8 k1 = *(const f16x8*)(pKt + (ks + 1) * 512);
            s0 = __builtin_amdgcn_mfma_f32_16x16x32_f16(q0, k0, s0, 0, 0, 0);
            s1 = __builtin_amdgcn_mfma_f32_16x16x32_f16(q1, k1, s1, 0, 0, 0);
        }
        const f32x4 sv = s0 + s1;
        _Float16* sPb = sP[kt2 & 1];
        const int n  = kt2 * 128 + 16 * wq_ + ql;
        const int mg = m0 + qr * 4;
        const int pi = ((16 * wq_ + ql) >> 3) * 16;
        {
            const float e = (n <= mg + 0) ? __expf(sv[0]) : 0.f;
            prs0 += e; sPb[(pi + qr * 4 + 0) * 8 + (ql & 7)] = (_Float16)e;
        }
        {
            const float e = (n <= mg + 1) ? __expf(sv[1]) : 0.f;
            prs1 += e; sPb[(pi + qr * 4 + 1) * 8 + (ql & 7)] = (_Float16)e;
        }
        {
            const float e = (n <= mg + 2) ? __expf(sv[2]) : 0.f;
            prs2 += e; sPb[(pi + qr * 4 + 2) * 8 + (ql & 7)] = (_Float16)e;
        }
        {
            const float e = (n <= mg + 3) ? __expf(sv[3]) : 0.f;
            prs3 += e; sPb[(pi + qr * 4 + 3) * 8 + (ql & 7)] = (_Float16)e;
        }
    };

    // ---- consumer: PV tile (hoisted P frags, simple loads) ----
    auto pv = [&](int kt2) {
        const _Float16* sPb = sP[kt2 & 1];
        const _Float16* pVt = pV0 + (long long)kt2 * 2048;
        f16x8 pfh[4];
#pragma unroll
        for (int k = 0; k < 4; ++k)
            pfh[k] = *(const f16x8*)&sPb[((k * 4 + qr) * 16 + ql) * 8];
#pragma unroll
        for (int ni = 0; ni < 6; ++ni) {
#pragma unroll
            for (int k = 0; k < 4; ++k) {
                const f16x8 vf = *(const f16x8*)(pVt + ni * 32768 + k * 512);
                oacc[ni] = __builtin_amdgcn_mfma_f32_16x16x32_f16(
                    pfh[k], vf, oacc[ni], 0, 0, 0);
            }
        }
    };

    // ---- pipelined main loop: producers on kt, consumers on kt-1 ----
    for (int kt = 0; kt < nt; ++kt) {
        if (isProd) qk_exp(kt);
        else if (kt > 0) pv(kt - 1);
        __syncthreads();           // sP[kt&1] published; consumers done with
                                   // sP[(kt-1)&1] before producers reuse it
    }
    // drain: last tile's PV + producer rowsum reduce
    if (isProd) {
        float r0 = prs0, r1 = prs1, r2 = prs2, r3 = prs3;
        r0 += __shfl_xor(r0, 1); r0 += __shfl_xor(r0, 2);
        r0 += __shfl_xor(r0, 4); r0 += __shfl_xor(r0, 8);
        r1 += __shfl_xor(r1, 1); r1 += __shfl_xor(r1, 2);
        r1 += __shfl_xor(r1, 4); r1 += __shfl_xor(r1, 8);
        r2 += __shfl_xor(r2, 1); r2 += __shfl_xor(r2, 2);
        r2 += __shfl_xor(r2, 4); r2 += __shfl_xor(r2, 8);
        r3 += __shfl_xor(r3, 1); r3 += __shfl_xor(r3, 2);
        r3 += __shfl_xor(r3, 4); r3 += __shfl_xor(r3, 8);
        if (ql == 0) {
            sRS[wq_][qr * 4 + 0] = r0; sRS[wq_][qr * 4 + 1] = r1;
            sRS[wq_][qr * 4 + 2] = r2; sRS[wq_][qr * 4 + 3] = r3;
        }
    } else {
        pv(nt - 1);
    }
    __syncthreads();

    // ---- consumers: normalize + O write ----
    if (!isProd) {
        float rt[4];
#pragma unroll
        for (int rr = 0; rr < 4; ++rr) {
            float t2 = 0.f;
#pragma unroll
            for (int w2 = 0; w2 < 8; ++w2) t2 += sRS[w2][qr * 4 + rr];
            rt[rr] = 1.f / t2;
        }
#pragma unroll
        for (int ni = 0; ni < 6; ++ni) {
#pragma unroll
            for (int rr = 0; rr < 4; ++rr) {
                out[(long long)(bz * 2048 + m0 + qr * 4 + rr) * 768
                    + 96 * wv_ + 16 * ni + ql] = oacc[ni][rr] * rt[rr];
            }
        }
    }
}

// ---------------- cvt: x -> f16 row-major, W -> f16 fragment-tiled ------
__global__ __launch_bounds__(256) void cvt_all(
    const float* __restrict__ x,  const float* __restrict__ wq,
    const float* __restrict__ wk, const float* __restrict__ wv,
    _Float16* __restrict__ xh, _Float16* __restrict__ Wht)
{
    const int ci = blockIdx.x * 256 + threadIdx.x;
    const int XC = 8192 * 768 / 8;               // 786432 x-chunks
    if (ci < XC) {
        const float4 v0 = ((const float4*)x)[ci * 2];
        const float4 v1 = ((const float4*)x)[ci * 2 + 1];
        f16x8 o = { (_Float16)v0.x, (_Float16)v0.y, (_Float16)v0.z, (_Float16)v0.w,
                    (_Float16)v1.x, (_Float16)v1.y, (_Float16)v1.z, (_Float16)v1.w };
        ((f16x8*)xh)[ci] = o;
    } else {
        // weights: one 16B tiled chunk per thread; writes coalesced.
        const int j = ci - XC;                   // < 2304*96 = 221184
        const int ql2 = j & 15, blk = j >> 4;
        const int c8 = blk % 96, grp = blk / 96;
        const int r = grp * 16 + ql2;            // 0..2303
        const int w = (r < 768) ? 0 : (r < 1536) ? 1 : 2;
        const float* src = (w == 0) ? wq : (w == 1) ? wk : wv;
        const int rr = r - w * 768;
        const float4 v0 = ((const float4*)src)[rr * 192 + c8 * 2];
        const float4 v1 = ((const float4*)src)[rr * 192 + c8 * 2 + 1];
        f16x8 o = { (_Float16)v0.x, (_Float16)v0.y, (_Float16)v0.z, (_Float16)v0.w,
                    (_Float16)v1.x, (_Float16)v1.y, (_Float16)v1.z, (_Float16)v1.w };
        ((f16x8*)Wht)[j] = o;
    }
}

extern "C" void kernel_launch(void* const* d_in, const int* in_sizes, int n_in,
                              void* d_out, int out_size, void* d_ws, size_t ws_size,
                              hipStream_t stream) {
    const float* x  = (const float*)d_in[0];
    const float* wq = (const float*)d_in[1];
    const float* wk = (const float*)d_in[2];
    const float* wv = (const float*)d_in[3];
    float* out = (float*)d_out;
    char* ws = (char*)d_ws;

    size_t off = 0;
    auto alloc = [&](size_t bytes) {
        void* p = ws + off;
        off = (off + bytes + 255) & ~(size_t)255;
        return p;
    };
    _Float16* xh  = (_Float16*)alloc(8192ll * 768 * 2);   // row-major
    _Float16* Wht = (_Float16*)alloc(2304ll * 768 * 2);   // frag-tiled
    _Float16* Qr  = (_Float16*)alloc(8192ll * 768 * 2);   // ROW-major, pre-scaled
    _Float16* Kt  = (_Float16*)alloc(8192ll * 768 * 2);   // frag-tiled
    _Float16* Vtt = (_Float16*)alloc(4ll * 768 * 2048 * 2);  // frag-tiled V^T

    const int XC = 8192 * 768 / 8, WC = 2304 * 96;
    cvt_all<<<(XC + WC) / 256, 256, 0, stream>>>(x, wq, wk, wv, xh, Wht);

    // Q/K/V projection: M=8192, N=2304, K=768 (128x128 tiles)
    gemm_qkv<<<dim3(18, 64, 1), 256, 0, stream>>>(xh, Wht, Qr, Kt, Vtt);

    // Fused causal attention: producer/consumer waves, one stripe per block
    fused_attn<<<dim3(512, 1, 1), 1024, 0, stream>>>(Qr, Kt, Vtt, out);
}